// Round 5
// baseline (50.277 us; speedup 1.0000x reference)
//
#include <hip/hip_runtime.h>
#include <hip/hip_bf16.h>

// Problem constants (KANLayer): B=8192, I=256, O=256, NUM_BASIS=7, ORDER=3
#define B_SZ 8192
#define I_SZ 256
#define O_SZ 256
#define KDIM 2048  // I_SZ * 8  (7 basis + 1 silu per input feature)
#define BM 32      // rows per block
#define BN 128     // output cols per block
#define BKT 64     // K per tile = 8 features
#define NT 32      // KDIM / BKT
#define NPART 256  // min/max partial rows

typedef __bf16 bf16x8 __attribute__((ext_vector_type(8)));
typedef float f32x4 __attribute__((ext_vector_type(4)));

// Kernel 1: per-column min/max partials. 256 blocks x 256 threads; block
// handles 32 rows via float4 loads (ILP), LDS-reduce over 4 row-subgroups,
// plain stores of one partial row per block (no atomics, no memset needed).
__global__ __launch_bounds__(256) void minmax_partial(
    const float* __restrict__ x, float* __restrict__ pmin,
    float* __restrict__ pmax) {
  const int cg = threadIdx.x & 63;  // column group (4 cols via float4)
  const int rs = threadIdx.x >> 6;  // row subgroup 0..3
  const int r0 = blockIdx.x * 32;
  const float* p = x + (size_t)(r0 + rs) * I_SZ + cg * 4;
  float4 mn = {1e30f, 1e30f, 1e30f, 1e30f};
  float4 mx = {-1e30f, -1e30f, -1e30f, -1e30f};
#pragma unroll
  for (int k = 0; k < 8; ++k) {
    const float4 v = *reinterpret_cast<const float4*>(p + (size_t)k * 4 * I_SZ);
    mn.x = fminf(mn.x, v.x); mn.y = fminf(mn.y, v.y);
    mn.z = fminf(mn.z, v.z); mn.w = fminf(mn.w, v.w);
    mx.x = fmaxf(mx.x, v.x); mx.y = fmaxf(mx.y, v.y);
    mx.z = fmaxf(mx.z, v.z); mx.w = fmaxf(mx.w, v.w);
  }
  __shared__ float rmn[4][I_SZ], rmx[4][I_SZ];
  *reinterpret_cast<float4*>(&rmn[rs][cg * 4]) = mn;
  *reinterpret_cast<float4*>(&rmx[rs][cg * 4]) = mx;
  __syncthreads();
  if (threadIdx.x < 64) {
    float4 a, b;
    const int c0 = threadIdx.x * 4;
    a.x = fminf(fminf(rmn[0][c0+0], rmn[1][c0+0]), fminf(rmn[2][c0+0], rmn[3][c0+0]));
    a.y = fminf(fminf(rmn[0][c0+1], rmn[1][c0+1]), fminf(rmn[2][c0+1], rmn[3][c0+1]));
    a.z = fminf(fminf(rmn[0][c0+2], rmn[1][c0+2]), fminf(rmn[2][c0+2], rmn[3][c0+2]));
    a.w = fminf(fminf(rmn[0][c0+3], rmn[1][c0+3]), fminf(rmn[2][c0+3], rmn[3][c0+3]));
    b.x = fmaxf(fmaxf(rmx[0][c0+0], rmx[1][c0+0]), fmaxf(rmx[2][c0+0], rmx[3][c0+0]));
    b.y = fmaxf(fmaxf(rmx[0][c0+1], rmx[1][c0+1]), fmaxf(rmx[2][c0+1], rmx[3][c0+1]));
    b.z = fmaxf(fmaxf(rmx[0][c0+2], rmx[1][c0+2]), fmaxf(rmx[2][c0+2], rmx[3][c0+2]));
    b.w = fmaxf(fmaxf(rmx[0][c0+3], rmx[1][c0+3]), fmaxf(rmx[2][c0+3], rmx[3][c0+3]));
    *reinterpret_cast<float4*>(&pmin[blockIdx.x * I_SZ + c0]) = a;
    *reinterpret_cast<float4*>(&pmax[blockIdx.x * I_SZ + c0]) = b;
  }
}

// Kernel 2: pack weights -> Wp[o, i*8+m] bf16, pre-swizzled (unit ^= o&7),
// PLUS (block 0) reduce the min/max partials into per-column centre and
// 1/half-width so the GEMM reads scales directly.
__global__ void pack_W(const float* __restrict__ bw,
                       const float* __restrict__ sw,
                       const float* __restrict__ coeff,
                       __hip_bfloat16* __restrict__ W,
                       const float* __restrict__ pmin,
                       const float* __restrict__ pmax,
                       float* __restrict__ cenrhw) {
  const int idx = blockIdx.x * blockDim.x + threadIdx.x;  // 0..O*I-1
  const int i = idx & (I_SZ - 1);
  const int o = idx >> 8;
  const float s = sw[idx];
  union { __hip_bfloat16 h[8]; float4 f4; } u;
#pragma unroll
  for (int m = 0; m < 7; ++m)
    u.h[m] = __float2bfloat16(coeff[(size_t)idx * 7 + m] * s);
  u.h[7] = __float2bfloat16(bw[idx]);
  const size_t off = (size_t)o * KDIM + (size_t)((i ^ (o & 7)) << 3);
  *reinterpret_cast<float4*>(&W[off]) = u.f4;

  if (blockIdx.x == 0) {
    const int c = threadIdx.x;
    float mn = 1e30f, mx = -1e30f;
#pragma unroll 8
    for (int p = 0; p < NPART; ++p) {
      mn = fminf(mn, pmin[p * I_SZ + c]);
      mx = fmaxf(mx, pmax[p * I_SZ + c]);
    }
    const float width = fmaxf(mx - mn, 0.01f);
    cenrhw[2 * c]     = 0.5f * (mx + mn);
    cenrhw[2 * c + 1] = 2.0f / width;   // 1/(0.5*width)
  }
}

// ---- async global->LDS 16B copy ----
__device__ __forceinline__ void async16(const __hip_bfloat16* g, __hip_bfloat16* l) {
  __builtin_amdgcn_global_load_lds(
      (const __attribute__((address_space(1))) void*)g,
      (__attribute__((address_space(3))) void*)l, 16, 0, 0);
}

// Kernel 3: fused basis-build + GEMM, counted-vmcnt pipeline (T3/T4).
// out[M, N] = A(x)[M, K] @ W[N, K]^T + bias; A built on the fly per K-tile.
// Block = 32 rows x 128 cols, 256 threads (4 waves), grid 512 = 2 blocks/CU.
// B triple-buffered (staged 2 tiles ahead, vmcnt(4) not 0); A double-buffered;
// ONE raw s_barrier per K-step.
__global__ __launch_bounds__(256, 2) void gemm_fused(
    const float* __restrict__ x, const __hip_bfloat16* __restrict__ W,
    const float* __restrict__ cenrhw, const float* __restrict__ bias,
    float* __restrict__ out) {
  __shared__ __align__(16) __hip_bfloat16 Alds[2][BM * BKT];   // 2 x 4KB
  __shared__ __align__(16) __hip_bfloat16 Blds[3][BN * BKT];   // 3 x 16KB
  __shared__ float2 scl[I_SZ];                                  // 2KB

  const int t = threadIdx.x;
  const int lane = t & 63;
  const int wave = t >> 6;            // 0..3 -> n-offset 32*wave
  const int fr = lane & 15, fk = lane >> 4;

  // XCD-aware bijective swizzle (512 blocks, %8==0)
  const int bid = blockIdx.x;
  const int swz = (bid & 7) * 64 + (bid >> 3);
  const int bm = swz >> 1, bn = swz & 1;
  const int r0 = bm * BM;    // batch-row base
  const int c0 = bn * BN;    // output-col base

  scl[t] = reinterpret_cast<const float2*>(cenrhw)[t];

  // A-build mapping: thread -> (row, feature-within-tile); one eval/thread
  const int arow = t >> 3;   // 0..31
  const int af_  = t & 7;    // 0..7
  const float* xp = x + (size_t)(r0 + arow) * I_SZ + af_;

  const __hip_bfloat16* gb0 = W + (size_t)(c0 + (t >> 3)) * KDIM + (t & 7) * 8;

  f32x4 acc[2][2] = {{{0.f,0.f,0.f,0.f},{0.f,0.f,0.f,0.f}},
                     {{0.f,0.f,0.f,0.f},{0.f,0.f,0.f,0.f}}};

  auto stageB = [&](int buf, int kt) {
    const size_t k0 = (size_t)kt * BKT;
    async16(gb0 + k0,                      &Blds[buf][t * 8]);
    async16(gb0 + k0 + (size_t)32 * KDIM,  &Blds[buf][2048 + t * 8]);
    async16(gb0 + k0 + (size_t)64 * KDIM,  &Blds[buf][4096 + t * 8]);
    async16(gb0 + k0 + (size_t)96 * KDIM,  &Blds[buf][6144 + t * 8]);
  };

  auto buildA = [&](int buf, int kt, float xv) {
    const int i = kt * 8 + af_;
    const float2 s = scl[i];
    float xn = (xv - s.x) * s.y;
    xn = fminf(fmaxf(xn, -2.0f), 2.0f);
    // d[j] = xn - KT[j], KT[j] = -1 + 0.2j (uniform knots)
    float d[11];
#pragma unroll
    for (int j = 0; j < 11; ++j) d[j] = xn - (-1.0f + 0.2f * j);
    float bas[7];
#pragma unroll
    for (int j = 0; j < 7; ++j)
      bas[j] = (d[j] >= 0.0f && d[j + 1] < 0.0f) ? 1.0f : 0.0f;
    if (d[7] == 0.0f) bas[6] = 1.0f;  // xe == KNOTS[7] special case
    // truncated de Boor; uniform knots: both denominators = 0.2k
#pragma unroll
    for (int k = 1; k <= 3; ++k) {
      const float rk = (k == 1) ? 5.0f : (k == 2) ? 2.5f : (1.0f / 0.6f);
#pragma unroll
      for (int j = 0; j < 7; ++j) {
        const float bn_ = (j < 6) ? bas[j + 1] : 0.0f;
        bas[j] = (d[j] * bas[j] - d[j + k + 1] * bn_) * rk;
      }
    }
    const float silu = xn / (1.0f + __expf(-xn));
    union { __hip_bfloat16 h[8]; float4 f4; } u;
#pragma unroll
    for (int m = 0; m < 7; ++m) u.h[m] = __float2bfloat16(bas[m]);
    u.h[7] = __float2bfloat16(silu);
    const int unit = af_ ^ (arow & 7);
    *reinterpret_cast<float4*>(&Alds[buf][arow * BKT + unit * 8]) = u.f4;
  };

  auto compute = [&](int bbuf, int abuf) {
    bf16x8 af[2][2], bg[2][2];
#pragma unroll
    for (int m = 0; m < 2; ++m)
#pragma unroll
      for (int kk = 0; kk < 2; ++kk) {
        const int row = m * 16 + fr;
        const int unit = ((kk << 2) | fk) ^ (row & 7);
        af[m][kk] = *reinterpret_cast<const bf16x8*>(&Alds[abuf][row * BKT + unit * 8]);
      }
#pragma unroll
    for (int n = 0; n < 2; ++n)
#pragma unroll
      for (int kk = 0; kk < 2; ++kk) {
        const int row = wave * 32 + n * 16 + fr;
        const int unit = ((kk << 2) | fk) ^ (row & 7);
        bg[n][kk] = *reinterpret_cast<const bf16x8*>(&Blds[bbuf][row * BKT + unit * 8]);
      }
    __builtin_amdgcn_s_setprio(1);
#pragma unroll
    for (int kk = 0; kk < 2; ++kk)
#pragma unroll
      for (int m = 0; m < 2; ++m)
#pragma unroll
        for (int n = 0; n < 2; ++n)
          acc[m][n] = __builtin_amdgcn_mfma_f32_16x16x32_bf16(
              af[m][kk], bg[n][kk], acc[m][n], 0, 0, 0);
    __builtin_amdgcn_s_setprio(0);
  };

  // prologue: x for tiles 0,1 loaded before the sync; stage B tiles 0,1.
  const float xv0 = xp[0];
  float xpf = xp[8];
  __syncthreads();              // scl visible (drains everything, once)
  stageB(0, 0);
  stageB(1, 1);
  buildA(0, 0, xv0);
  asm volatile("s_waitcnt vmcnt(4) lgkmcnt(0)" ::: "memory");  // B0 + A0 ready
  __builtin_amdgcn_s_barrier();
  asm volatile("" ::: "memory");

  int bcur = 0;  // B buffer for tile kt (kt % 3)
  for (int kt = 0; kt < NT - 1; ++kt) {
    const int bnxt = (bcur == 2) ? 0 : bcur + 1;          // (kt+1) % 3
    const int bpre = (bnxt == 2) ? 0 : bnxt + 1;          // (kt+2) % 3
    if (kt + 2 < NT) {
      stageB(bpre, kt + 2);
      const float xpf2 = xp[(kt + 2) * 8];
      buildA((kt + 1) & 1, kt + 1, xpf);
      xpf = xpf2;
    } else {
      buildA((kt + 1) & 1, kt + 1, xpf);
    }
    compute(bcur, kt & 1);
    // B(kt+1) staged (issued last iter; <=4 newer vmem in flight) + A(kt+1)
    if (kt < NT - 2)
      asm volatile("s_waitcnt vmcnt(4) lgkmcnt(0)" ::: "memory");
    else
      asm volatile("s_waitcnt vmcnt(0) lgkmcnt(0)" ::: "memory");
    __builtin_amdgcn_s_barrier();
    asm volatile("" ::: "memory");
    bcur = bnxt;
  }
  compute(bcur, (NT - 1) & 1);

  // epilogue: C/D layout col=lane&15, row=(lane>>4)*4+reg  [m89/m91]
#pragma unroll
  for (int m = 0; m < 2; ++m)
#pragma unroll
    for (int n = 0; n < 2; ++n) {
      const int col = c0 + wave * 32 + n * 16 + fr;
      const float bc = bias[col];
#pragma unroll
      for (int r = 0; r < 4; ++r) {
        const int row = r0 + m * 16 + fk * 4 + r;
        out[(size_t)row * O_SZ + col] = acc[m][n][r] + bc;
      }
    }
}

extern "C" void kernel_launch(void* const* d_in, const int* in_sizes, int n_in,
                              void* d_out, int out_size, void* d_ws, size_t ws_size,
                              hipStream_t stream) {
  const float* x     = (const float*)d_in[0];
  const float* bw    = (const float*)d_in[1];
  const float* sw    = (const float*)d_in[2];
  const float* coeff = (const float*)d_in[3];
  const float* bias  = (const float*)d_in[4];
  float* out = (float*)d_out;

  char* ws = (char*)d_ws;
  __hip_bfloat16* Wbuf = (__hip_bfloat16*)ws;                    // 1 MiB
  float* pmin   = (float*)(ws + (size_t)O_SZ * KDIM * 2);        // 256 KiB
  float* pmax   = pmin + NPART * I_SZ;                           // 256 KiB
  float* cenrhw = pmax + NPART * I_SZ;                           // 2 KiB

  minmax_partial<<<NPART, 256, 0, stream>>>(x, pmin, pmax);
  pack_W<<<(O_SZ * I_SZ) / 256, 256, 0, stream>>>(bw, sw, coeff, Wbuf,
                                                  pmin, pmax, cenrhw);
  gemm_fused<<<(B_SZ / BM) * (O_SZ / BN), 256, 0, stream>>>(x, Wbuf, cenrhw,
                                                            bias, out);
}